// Round 1
// baseline (1201.353 us; speedup 1.0000x reference)
//
#include <hip/hip_runtime.h>
#include <math.h>

#define B_  8
#define D_  256
#define N_  2048
#define M_  2048
#define H_  4

// ---------------------------------------------------------------------------
// Generic pointwise conv (kernel_size=1): out[b,o,n] = sum_c W[o,c]*in(b,c,n)+bias[o]
// in(b,c,n) = c < split ? inA[b,c,n] : inB[b,c-split,n]   (virtual concat)
// Tile: 64 out x 64 n per block, 256 threads, 4x4 per thread, K-chunk 32.
// ---------------------------------------------------------------------------
__global__ __launch_bounds__(256) void pw_conv(
    const float* __restrict__ W, const float* __restrict__ bias,
    const float* __restrict__ inA, const float* __restrict__ inB,
    int split, int Din, float* __restrict__ out)
{
    __shared__ float Ws[64][33];   // [o][kk], pad 33 -> conflict-free col reads
    __shared__ float Xs[32][64];   // [kk][n]
    const int b  = blockIdx.z;
    const int o0 = blockIdx.y * 64;
    const int n0 = blockIdx.x * 64;
    const int Dout = gridDim.y * 64;
    const int tid = threadIdx.x;
    const int tx = tid & 15, ty = tid >> 4;

    float acc[4][4] = {};

    for (int k0 = 0; k0 < Din; k0 += 32) {
        // stage W chunk [64 o][32 k] (coalesced along k)
        #pragma unroll
        for (int u = 0; u < 8; ++u) {
            const int l = u * 256 + tid;
            Ws[l >> 5][l & 31] = W[(size_t)(o0 + (l >> 5)) * Din + k0 + (l & 31)];
        }
        // stage X chunk [32 k][64 n] (coalesced along n)
        #pragma unroll
        for (int u = 0; u < 8; ++u) {
            const int l = u * 256 + tid;
            const int n = l & 63, kk = l >> 6;
            const int c = k0 + kk;
            float val;
            if (c < split)
                val = inA[((size_t)b * split + c) * N_ + n0 + n];
            else
                val = inB[((size_t)b * (Din - split) + (c - split)) * N_ + n0 + n];
            Xs[kk][n] = val;
        }
        __syncthreads();
        #pragma unroll 8
        for (int kk = 0; kk < 32; ++kk) {
            const float a0 = Ws[ty*4+0][kk];
            const float a1 = Ws[ty*4+1][kk];
            const float a2 = Ws[ty*4+2][kk];
            const float a3 = Ws[ty*4+3][kk];
            const float4 bv = *(const float4*)&Xs[kk][tx*4];
            acc[0][0] += a0*bv.x; acc[0][1] += a0*bv.y; acc[0][2] += a0*bv.z; acc[0][3] += a0*bv.w;
            acc[1][0] += a1*bv.x; acc[1][1] += a1*bv.y; acc[1][2] += a1*bv.z; acc[1][3] += a1*bv.w;
            acc[2][0] += a2*bv.x; acc[2][1] += a2*bv.y; acc[2][2] += a2*bv.z; acc[2][3] += a2*bv.w;
            acc[3][0] += a3*bv.x; acc[3][1] += a3*bv.y; acc[3][2] += a3*bv.z; acc[3][3] += a3*bv.w;
        }
        __syncthreads();
    }

    #pragma unroll
    for (int i = 0; i < 4; ++i) {
        const int o = o0 + ty*4 + i;
        const float bi = bias[o];
        float4 r;
        r.x = acc[i][0] + bi; r.y = acc[i][1] + bi;
        r.z = acc[i][2] + bi; r.w = acc[i][3] + bi;
        *(float4*)&out[((size_t)b * Dout + o) * N_ + n0 + tx*4] = r;
    }
}

// ---------------------------------------------------------------------------
// Flash attention with multiplicative mask.
// Head split per torch .view: channel d = dh*H + h.
// Block: one (b, h, 64-row n-tile). Online softmax over m-tiles of 64.
// KPs buffer holds K during QK^T, then P (after a barrier).
// Vs is XOR-swizzled along m to avoid 8-way bank conflicts in PV reads.
// ---------------------------------------------------------------------------
#define VSWZ(row, m) ((m) ^ ((((row) >> 2) & 7) << 2))

__global__ __launch_bounds__(256) void attn_flash(
    const float* __restrict__ q, const float* __restrict__ k,
    const float* __restrict__ v, const float* __restrict__ mask,
    float* __restrict__ attnout)
{
    __shared__ float Qs[64][68];    // [dh][n]
    __shared__ float KPs[64][68];   // [dh][m] then [n][m]
    __shared__ float Vs[64][64];    // [dh][m swizzled]
    const int b  = blockIdx.z;
    const int h  = blockIdx.y;
    const int n0 = blockIdx.x * 64;
    const int tid = threadIdx.x;
    const int tx = tid & 15, ty = tid >> 4;

    #pragma unroll
    for (int u = 0; u < 16; ++u) {
        const int l = u * 256 + tid;
        const int n = l & 63, dh = l >> 6;
        Qs[dh][n] = q[((size_t)b * D_ + dh * H_ + h) * N_ + n0 + n];
    }

    float oacc[4][4] = {};
    float mrun[4] = {-INFINITY, -INFINITY, -INFINITY, -INFINITY};
    float lrun[4] = {0.f, 0.f, 0.f, 0.f};

    __syncthreads();

    for (int m0 = 0; m0 < M_; m0 += 64) {
        // stage K and V tiles [64 dh][64 m]
        #pragma unroll
        for (int u = 0; u < 16; ++u) {
            const int l = u * 256 + tid;
            const int m = l & 63, dh = l >> 6;
            const size_t si = ((size_t)b * D_ + dh * H_ + h) * (size_t)M_ + m0 + m;
            KPs[dh][m] = k[si];
            Vs[dh][VSWZ(dh, m)] = v[si];
        }
        __syncthreads();

        // S[n][m] = sum_dh Q[dh][n] * K[dh][m]
        float sacc[4][4] = {};
        #pragma unroll 8
        for (int dh = 0; dh < 64; ++dh) {
            const float4 qa = *(const float4*)&Qs[dh][ty*4];
            const float4 kb = *(const float4*)&KPs[dh][tx*4];
            const float qa_[4] = {qa.x, qa.y, qa.z, qa.w};
            const float kb_[4] = {kb.x, kb.y, kb.z, kb.w};
            #pragma unroll
            for (int i = 0; i < 4; ++i)
                #pragma unroll
                for (int j = 0; j < 4; ++j)
                    sacc[i][j] += qa_[i] * kb_[j];
        }
        __syncthreads();   // K reads done; KPs becomes P storage

        // mask, online softmax (rows n = ty*4+i, 16 tx lanes share a row)
        #pragma unroll
        for (int i = 0; i < 4; ++i) {
            const float4 mv = *(const float4*)&mask[((size_t)b * N_ + n0 + ty*4 + i) * (size_t)M_ + m0 + tx*4];
            float s_[4];
            s_[0] = sacc[i][0] * 0.125f * mv.x;
            s_[1] = sacc[i][1] * 0.125f * mv.y;
            s_[2] = sacc[i][2] * 0.125f * mv.z;
            s_[3] = sacc[i][3] * 0.125f * mv.w;
            float tmax = fmaxf(fmaxf(s_[0], s_[1]), fmaxf(s_[2], s_[3]));
            tmax = fmaxf(tmax, __shfl_xor(tmax, 1, 16));
            tmax = fmaxf(tmax, __shfl_xor(tmax, 2, 16));
            tmax = fmaxf(tmax, __shfl_xor(tmax, 4, 16));
            tmax = fmaxf(tmax, __shfl_xor(tmax, 8, 16));
            const float nm = fmaxf(mrun[i], tmax);
            const float corr = __expf(mrun[i] - nm);   // exp(-inf)=0 on first tile
            float p_[4], psum = 0.f;
            #pragma unroll
            for (int j = 0; j < 4; ++j) { p_[j] = __expf(s_[j] - nm); psum += p_[j]; }
            psum += __shfl_xor(psum, 1, 16);
            psum += __shfl_xor(psum, 2, 16);
            psum += __shfl_xor(psum, 4, 16);
            psum += __shfl_xor(psum, 8, 16);
            lrun[i] = lrun[i] * corr + psum;
            mrun[i] = nm;
            #pragma unroll
            for (int j = 0; j < 4; ++j) oacc[i][j] *= corr;
            *(float4*)&KPs[ty*4+i][tx*4] = make_float4(p_[0], p_[1], p_[2], p_[3]);
        }
        __syncthreads();

        // O[n][dh] += P[n][m] * V[dh][m]
        #pragma unroll 4
        for (int mm = 0; mm < 64; mm += 4) {
            float4 pp[4], vv[4];
            #pragma unroll
            for (int i = 0; i < 4; ++i) pp[i] = *(const float4*)&KPs[ty*4+i][mm];
            #pragma unroll
            for (int j = 0; j < 4; ++j) {
                const int row = tx*4 + j;
                vv[j] = *(const float4*)&Vs[row][VSWZ(row, mm)];
            }
            #pragma unroll
            for (int i = 0; i < 4; ++i) {
                #pragma unroll
                for (int j = 0; j < 4; ++j) {
                    oacc[i][j] += pp[i].x*vv[j].x + pp[i].y*vv[j].y
                                + pp[i].z*vv[j].z + pp[i].w*vv[j].w;
                }
            }
        }
        __syncthreads();   // protect K/V overwrite next iteration
    }

    // write attn[b, dh*H+h, n] with dh = tx*4+j, n = n0+ty*4+i
    #pragma unroll
    for (int i = 0; i < 4; ++i) {
        const float invl = 1.f / lrun[i];
        #pragma unroll
        for (int j = 0; j < 4; ++j) {
            attnout[((size_t)b * D_ + (tx*4 + j) * H_ + h) * N_ + n0 + ty*4 + i] = oacc[i][j] * invl;
        }
    }
}

// ---------------------------------------------------------------------------
// InstanceNorm1d (affine=False) + ReLU, in place. One block per (b, channel).
// ---------------------------------------------------------------------------
__global__ __launch_bounds__(256) void inorm_relu(float* __restrict__ y)
{
    const int tid = threadIdx.x;
    float* row = y + (size_t)blockIdx.x * N_;
    float s = 0.f, s2 = 0.f;
    #pragma unroll
    for (int u = 0; u < 2; ++u) {
        const float4 v4 = *(const float4*)&row[u*1024 + tid*4];
        s  += v4.x + v4.y + v4.z + v4.w;
        s2 += v4.x*v4.x + v4.y*v4.y + v4.z*v4.z + v4.w*v4.w;
    }
    #pragma unroll
    for (int off = 1; off < 64; off <<= 1) {
        s  += __shfl_xor(s,  off);
        s2 += __shfl_xor(s2, off);
    }
    __shared__ float red[8];
    const int w = tid >> 6;
    if ((tid & 63) == 0) { red[w] = s; red[w + 4] = s2; }
    __syncthreads();
    s  = red[0] + red[1] + red[2] + red[3];
    s2 = red[4] + red[5] + red[6] + red[7];
    const float mean = s * (1.f / N_);
    const float var  = s2 * (1.f / N_) - mean * mean;
    const float inv  = rsqrtf(var + 1e-5f);
    #pragma unroll
    for (int u = 0; u < 2; ++u) {
        float4 v4 = *(float4*)&row[u*1024 + tid*4];
        v4.x = fmaxf((v4.x - mean) * inv, 0.f);
        v4.y = fmaxf((v4.y - mean) * inv, 0.f);
        v4.z = fmaxf((v4.z - mean) * inv, 0.f);
        v4.w = fmaxf((v4.w - mean) * inv, 0.f);
        *(float4*)&row[u*1024 + tid*4] = v4;
    }
}

// ---------------------------------------------------------------------------
extern "C" void kernel_launch(void* const* d_in, const int* in_sizes, int n_in,
                              void* d_out, int out_size, void* d_ws, size_t ws_size,
                              hipStream_t stream)
{
    const float* x    = (const float*)d_in[0];
    const float* srcp = (const float*)d_in[1];
    const float* mask = (const float*)d_in[2];
    const float* Wq = (const float*)d_in[3];
    const float* bq = (const float*)d_in[4];
    const float* Wk = (const float*)d_in[5];
    const float* bk = (const float*)d_in[6];
    const float* Wv = (const float*)d_in[7];
    const float* bv = (const float*)d_in[8];
    const float* Wm = (const float*)d_in[9];
    const float* bm = (const float*)d_in[10];
    const float* W1 = (const float*)d_in[11];
    const float* b1 = (const float*)d_in[12];
    const float* W2 = (const float*)d_in[13];
    const float* b2 = (const float*)d_in[14];
    float* out = (float*)d_out;

    float* ws = (float*)d_ws;
    const size_t sz = (size_t)B_ * D_ * N_;   // 4,194,304 floats
    float* qb = ws;             // [B,D,N]
    float* kb = ws + sz;        // [B,D,N]
    float* vb = ws + 2 * sz;    // [B,D,N]
    float* ab = ws + 3 * sz;    // [B,D,N] attn output
    float* msg = qb;            // message reuses q region (q dead after attn)
    float* y1 = ws + sz;        // [B,2D,N] reuses k+v regions (dead after attn)
    // total ws: 4*sz floats = 64 MiB

    const dim3 blk(256);
    const dim3 g1(N_/64, D_/64, B_);

    pw_conv<<<g1, blk, 0, stream>>>(Wq, bq, x,    x,    D_, D_, qb);
    pw_conv<<<g1, blk, 0, stream>>>(Wk, bk, srcp, srcp, D_, D_, kb);
    pw_conv<<<g1, blk, 0, stream>>>(Wv, bv, srcp, srcp, D_, D_, vb);

    attn_flash<<<dim3(N_/64, H_, B_), blk, 0, stream>>>(qb, kb, vb, mask, ab);

    pw_conv<<<g1, blk, 0, stream>>>(Wm, bm, ab, ab, D_, D_, msg);

    // y1 = W1 @ concat(x, message) + b1   (virtual concat via split pointer)
    pw_conv<<<dim3(N_/64, (2*D_)/64, B_), blk, 0, stream>>>(W1, b1, x, msg, D_, 2*D_, y1);

    inorm_relu<<<dim3(B_ * 2 * D_), blk, 0, stream>>>(y1);

    pw_conv<<<dim3(N_/64, D_/64, B_), blk, 0, stream>>>(W2, b2, y1, y1, 2*D_, 2*D_, out);
}

// Round 2
// 721.802 us; speedup vs baseline: 1.6644x; 1.6644x over previous
//
#include <hip/hip_runtime.h>
#include <hip/hip_bf16.h>
#include <math.h>

#define B_  8
#define D_  256
#define N_  2048
#define M_  2048
#define H_  4

typedef __attribute__((ext_vector_type(8))) short bf16x8;
typedef __attribute__((ext_vector_type(4))) float f32x4;

static __device__ __forceinline__ unsigned short f2bf(float f) {
    __hip_bfloat16 h = __float2bfloat16(f);
    return *reinterpret_cast<unsigned short*>(&h);
}

// ---------------------------------------------------------------------------
// Generic pointwise conv (fp32 in/out), virtual concat via (inA,inB,split).
// ---------------------------------------------------------------------------
__global__ __launch_bounds__(256) void pw_conv(
    const float* __restrict__ W, const float* __restrict__ bias,
    const float* __restrict__ inA, const float* __restrict__ inB,
    int split, int Din, float* __restrict__ out)
{
    __shared__ float Ws[64][33];
    __shared__ float Xs[32][64];
    const int b  = blockIdx.z;
    const int o0 = blockIdx.y * 64;
    const int n0 = blockIdx.x * 64;
    const int Dout = gridDim.y * 64;
    const int tid = threadIdx.x;
    const int tx = tid & 15, ty = tid >> 4;

    float acc[4][4] = {};

    for (int k0 = 0; k0 < Din; k0 += 32) {
        #pragma unroll
        for (int u = 0; u < 8; ++u) {
            const int l = u * 256 + tid;
            Ws[l >> 5][l & 31] = W[(size_t)(o0 + (l >> 5)) * Din + k0 + (l & 31)];
        }
        #pragma unroll
        for (int u = 0; u < 8; ++u) {
            const int l = u * 256 + tid;
            const int n = l & 63, kk = l >> 6;
            const int c = k0 + kk;
            float val;
            if (c < split)
                val = inA[((size_t)b * split + c) * N_ + n0 + n];
            else
                val = inB[((size_t)b * (Din - split) + (c - split)) * N_ + n0 + n];
            Xs[kk][n] = val;
        }
        __syncthreads();
        #pragma unroll 8
        for (int kk = 0; kk < 32; ++kk) {
            const float a0 = Ws[ty*4+0][kk];
            const float a1 = Ws[ty*4+1][kk];
            const float a2 = Ws[ty*4+2][kk];
            const float a3 = Ws[ty*4+3][kk];
            const float4 bv = *(const float4*)&Xs[kk][tx*4];
            acc[0][0] += a0*bv.x; acc[0][1] += a0*bv.y; acc[0][2] += a0*bv.z; acc[0][3] += a0*bv.w;
            acc[1][0] += a1*bv.x; acc[1][1] += a1*bv.y; acc[1][2] += a1*bv.z; acc[1][3] += a1*bv.w;
            acc[2][0] += a2*bv.x; acc[2][1] += a2*bv.y; acc[2][2] += a2*bv.z; acc[2][3] += a2*bv.w;
            acc[3][0] += a3*bv.x; acc[3][1] += a3*bv.y; acc[3][2] += a3*bv.z; acc[3][3] += a3*bv.w;
        }
        __syncthreads();
    }

    #pragma unroll
    for (int i = 0; i < 4; ++i) {
        const int o = o0 + ty*4 + i;
        const float bi = bias[o];
        float4 r;
        r.x = acc[i][0] + bi; r.y = acc[i][1] + bi;
        r.z = acc[i][2] + bi; r.w = acc[i][3] + bi;
        *(float4*)&out[((size_t)b * Dout + o) * N_ + n0 + tx*4] = r;
    }
}

// ---------------------------------------------------------------------------
// Pointwise conv writing TRANSPOSED bf16 output qt[b, h, pos, dh]
// (head split per torch .view: channel o = dh*H + h).
// ---------------------------------------------------------------------------
__global__ __launch_bounds__(256) void pw_conv_qk(
    const float* __restrict__ W, const float* __restrict__ bias,
    const float* __restrict__ in, unsigned short* __restrict__ outT)
{
    __shared__ float Ws[64][33];
    __shared__ float Xs[32][64];
    __shared__ unsigned short T[64][66];   // [n][o], padded
    const int b  = blockIdx.z;
    const int o0 = blockIdx.y * 64;
    const int n0 = blockIdx.x * 64;
    const int tid = threadIdx.x;
    const int tx = tid & 15, ty = tid >> 4;

    float acc[4][4] = {};

    for (int k0 = 0; k0 < D_; k0 += 32) {
        #pragma unroll
        for (int u = 0; u < 8; ++u) {
            const int l = u * 256 + tid;
            Ws[l >> 5][l & 31] = W[(size_t)(o0 + (l >> 5)) * D_ + k0 + (l & 31)];
        }
        #pragma unroll
        for (int u = 0; u < 8; ++u) {
            const int l = u * 256 + tid;
            const int n = l & 63, kk = l >> 6;
            Xs[kk][n] = in[((size_t)b * D_ + k0 + kk) * N_ + n0 + n];
        }
        __syncthreads();
        #pragma unroll 8
        for (int kk = 0; kk < 32; ++kk) {
            const float a0 = Ws[ty*4+0][kk];
            const float a1 = Ws[ty*4+1][kk];
            const float a2 = Ws[ty*4+2][kk];
            const float a3 = Ws[ty*4+3][kk];
            const float4 bv = *(const float4*)&Xs[kk][tx*4];
            acc[0][0] += a0*bv.x; acc[0][1] += a0*bv.y; acc[0][2] += a0*bv.z; acc[0][3] += a0*bv.w;
            acc[1][0] += a1*bv.x; acc[1][1] += a1*bv.y; acc[1][2] += a1*bv.z; acc[1][3] += a1*bv.w;
            acc[2][0] += a2*bv.x; acc[2][1] += a2*bv.y; acc[2][2] += a2*bv.z; acc[2][3] += a2*bv.w;
            acc[3][0] += a3*bv.x; acc[3][1] += a3*bv.y; acc[3][2] += a3*bv.z; acc[3][3] += a3*bv.w;
        }
        __syncthreads();
    }

    // bias + bf16 + transpose into LDS [n][o]
    #pragma unroll
    for (int i = 0; i < 4; ++i) {
        const float bi = bias[o0 + ty*4 + i];
        #pragma unroll
        for (int j = 0; j < 4; ++j)
            T[tx*4+j][ty*4+i] = f2bf(acc[i][j] + bi);
    }
    __syncthreads();

    // write qt[b, h, n0+n, dh0 + dq*4 .. +3]  (dh0 = o0/4, 16 dh per block)
    const int dh0 = o0 >> 2;
    #pragma unroll
    for (int u = 0; u < 4; ++u) {
        const int idx = u * 256 + tid;
        const int dq = idx & 3, n = (idx >> 2) & 63, h = idx >> 8;
        ushort4 val;
        val.x = T[n][(dq*4 + 0)*4 + h];
        val.y = T[n][(dq*4 + 1)*4 + h];
        val.z = T[n][(dq*4 + 2)*4 + h];
        val.w = T[n][(dq*4 + 3)*4 + h];
        *(ushort4*)&outT[(((size_t)b * H_ + h) * N_ + n0 + n) * 64 + dh0 + dq*4] = val;
    }
}

// ---------------------------------------------------------------------------
// Pointwise conv writing bf16 output in native [b, d, pos] layout (for V).
// ---------------------------------------------------------------------------
__global__ __launch_bounds__(256) void pw_conv_v(
    const float* __restrict__ W, const float* __restrict__ bias,
    const float* __restrict__ in, unsigned short* __restrict__ outb)
{
    __shared__ float Ws[64][33];
    __shared__ float Xs[32][64];
    const int b  = blockIdx.z;
    const int o0 = blockIdx.y * 64;
    const int n0 = blockIdx.x * 64;
    const int tid = threadIdx.x;
    const int tx = tid & 15, ty = tid >> 4;

    float acc[4][4] = {};

    for (int k0 = 0; k0 < D_; k0 += 32) {
        #pragma unroll
        for (int u = 0; u < 8; ++u) {
            const int l = u * 256 + tid;
            Ws[l >> 5][l & 31] = W[(size_t)(o0 + (l >> 5)) * D_ + k0 + (l & 31)];
        }
        #pragma unroll
        for (int u = 0; u < 8; ++u) {
            const int l = u * 256 + tid;
            const int n = l & 63, kk = l >> 6;
            Xs[kk][n] = in[((size_t)b * D_ + k0 + kk) * N_ + n0 + n];
        }
        __syncthreads();
        #pragma unroll 8
        for (int kk = 0; kk < 32; ++kk) {
            const float a0 = Ws[ty*4+0][kk];
            const float a1 = Ws[ty*4+1][kk];
            const float a2 = Ws[ty*4+2][kk];
            const float a3 = Ws[ty*4+3][kk];
            const float4 bv = *(const float4*)&Xs[kk][tx*4];
            acc[0][0] += a0*bv.x; acc[0][1] += a0*bv.y; acc[0][2] += a0*bv.z; acc[0][3] += a0*bv.w;
            acc[1][0] += a1*bv.x; acc[1][1] += a1*bv.y; acc[1][2] += a1*bv.z; acc[1][3] += a1*bv.w;
            acc[2][0] += a2*bv.x; acc[2][1] += a2*bv.y; acc[2][2] += a2*bv.z; acc[2][3] += a2*bv.w;
            acc[3][0] += a3*bv.x; acc[3][1] += a3*bv.y; acc[3][2] += a3*bv.z; acc[3][3] += a3*bv.w;
        }
        __syncthreads();
    }

    #pragma unroll
    for (int i = 0; i < 4; ++i) {
        const int o = o0 + ty*4 + i;
        const float bi = bias[o];
        ushort4 r;
        r.x = f2bf(acc[i][0] + bi); r.y = f2bf(acc[i][1] + bi);
        r.z = f2bf(acc[i][2] + bi); r.w = f2bf(acc[i][3] + bi);
        *(ushort4*)&outb[((size_t)b * D_ + o) * N_ + n0 + tx*4] = r;
    }
}

// ---------------------------------------------------------------------------
// MFMA flash attention (bf16 inputs, fp32 softmax/accum).
// qt/kt: [b,h,pos,dh] bf16. vbf: [b,d,pos] bf16. mask: fp32 [b,n,m].
// out: fp32 [b,d,n]. Grid (N/64, H, B), 256 threads (4 waves, 16 n-rows each).
// LDS tiles XOR-swizzled: col ^= (row&7)<<3 (granule 8 bf16 = 16B).
// ---------------------------------------------------------------------------
__global__ __launch_bounds__(256) void attn_mfma(
    const unsigned short* __restrict__ qt, const unsigned short* __restrict__ kt,
    const unsigned short* __restrict__ vbf, const float* __restrict__ mask,
    float* __restrict__ out)
{
    __shared__ __align__(16) unsigned short SH[4 * 64 * 64];   // Qs|Ks|Vs|Ps, 32 KB
    unsigned short* Qs = SH;
    unsigned short* Ks = SH + 4096;
    unsigned short* Vs = SH + 8192;
    unsigned short* Ps = SH + 12288;

    const int b = blockIdx.z, h = blockIdx.y, n0 = blockIdx.x * 64;
    const int tid = threadIdx.x;
    const int w = tid >> 6, lane = tid & 63;
    const int ln = lane & 15, g = lane >> 4;
    const int rsw = (ln & 7) << 3;   // read swizzle for rows with row&7 == ln&7

    // ---- stage Q [n][dh] (already transposed in global) ----
    #pragma unroll
    for (int u = 0; u < 4; ++u) {
        const int idx = u * 256 + tid;
        const int ch = idx & 15, n = idx >> 4;
        const ushort4 v = *(const ushort4*)&qt[(((size_t)b * H_ + h) * N_ + n0 + n) * 64 + ch*4];
        *(ushort4*)&Qs[n * 64 + ((ch*4) ^ ((n & 7) << 3))] = v;
    }

    f32x4 oacc[4];
    #pragma unroll
    for (int f = 0; f < 4; ++f) oacc[f] = (f32x4){0.f, 0.f, 0.f, 0.f};
    float mrun[4] = {-INFINITY, -INFINITY, -INFINITY, -INFINITY};
    float lrun[4] = {0.f, 0.f, 0.f, 0.f};

    __syncthreads();

    // Q A-frags are loop-invariant: rows w*16+ln, k = dh
    bf16x8 a_q[2];
    #pragma unroll
    for (int ks = 0; ks < 2; ++ks)
        a_q[ks] = *(const bf16x8*)&Qs[(w*16 + ln) * 64 + ((ks*32 + g*8) ^ rsw)];

    for (int m0 = 0; m0 < M_; m0 += 64) {
        // ---- stage K [m][dh], V [dh][m] ----
        #pragma unroll
        for (int u = 0; u < 4; ++u) {
            const int idx = u * 256 + tid;
            const int ch = idx & 15, r = idx >> 4;
            const ushort4 kv = *(const ushort4*)&kt[(((size_t)b * H_ + h) * M_ + m0 + r) * 64 + ch*4];
            *(ushort4*)&Ks[r * 64 + ((ch*4) ^ ((r & 7) << 3))] = kv;
            const ushort4 vv = *(const ushort4*)&vbf[((size_t)b * D_ + r * H_ + h) * M_ + m0 + ch*4];
            *(ushort4*)&Vs[r * 64 + ((ch*4) ^ ((r & 7) << 3))] = vv;
        }
        __syncthreads();

        // ---- preload mask: rows n = w*16+g*4+r, cols m0+f*16+ln ----
        float mk[4][4];
        #pragma unroll
        for (int r = 0; r < 4; ++r)
            #pragma unroll
            for (int f = 0; f < 4; ++f)
                mk[r][f] = mask[((size_t)b * N_ + n0 + w*16 + g*4 + r) * (size_t)M_ + m0 + f*16 + ln];

        // ---- S = Q^T K : 4 m-frags x 2 k-steps ----
        f32x4 sacc[4];
        #pragma unroll
        for (int f = 0; f < 4; ++f) sacc[f] = (f32x4){0.f, 0.f, 0.f, 0.f};
        #pragma unroll
        for (int ks = 0; ks < 2; ++ks)
            #pragma unroll
            for (int f = 0; f < 4; ++f) {
                const bf16x8 bk = *(const bf16x8*)&Ks[(f*16 + ln) * 64 + ((ks*32 + g*8) ^ rsw)];
                sacc[f] = __builtin_amdgcn_mfma_f32_16x16x32_bf16(a_q[ks], bk, sacc[f], 0, 0, 0);
            }

        // ---- online softmax (rows n = w*16 + g*4 + r) ----
        #pragma unroll
        for (int r = 0; r < 4; ++r) {
            float s0 = sacc[0][r] * 0.125f * mk[r][0];
            float s1 = sacc[1][r] * 0.125f * mk[r][1];
            float s2 = sacc[2][r] * 0.125f * mk[r][2];
            float s3 = sacc[3][r] * 0.125f * mk[r][3];
            float tmax = fmaxf(fmaxf(s0, s1), fmaxf(s2, s3));
            tmax = fmaxf(tmax, __shfl_xor(tmax, 1, 16));
            tmax = fmaxf(tmax, __shfl_xor(tmax, 2, 16));
            tmax = fmaxf(tmax, __shfl_xor(tmax, 4, 16));
            tmax = fmaxf(tmax, __shfl_xor(tmax, 8, 16));
            const float nm = fmaxf(mrun[r], tmax);
            const float corr = __expf(mrun[r] - nm);
            const float p0 = __expf(s0 - nm);
            const float p1 = __expf(s1 - nm);
            const float p2 = __expf(s2 - nm);
            const float p3 = __expf(s3 - nm);
            float ps = p0 + p1 + p2 + p3;
            ps += __shfl_xor(ps, 1, 16);
            ps += __shfl_xor(ps, 2, 16);
            ps += __shfl_xor(ps, 4, 16);
            ps += __shfl_xor(ps, 8, 16);
            lrun[r] = lrun[r] * corr + ps;
            mrun[r] = nm;
            #pragma unroll
            for (int f = 0; f < 4; ++f) oacc[f][r] *= corr;
            const int row = w*16 + g*4 + r;
            const int rs2 = (row & 7) << 3;
            Ps[row * 64 + ((0*16 + ln) ^ rs2)] = f2bf(p0);
            Ps[row * 64 + ((1*16 + ln) ^ rs2)] = f2bf(p1);
            Ps[row * 64 + ((2*16 + ln) ^ rs2)] = f2bf(p2);
            Ps[row * 64 + ((3*16 + ln) ^ rs2)] = f2bf(p3);
        }
        __syncthreads();

        // ---- O += P V^T : 4 dh-frags x 2 k-steps (k = m) ----
        #pragma unroll
        for (int ks = 0; ks < 2; ++ks) {
            const bf16x8 ap = *(const bf16x8*)&Ps[(w*16 + ln) * 64 + ((ks*32 + g*8) ^ rsw)];
            #pragma unroll
            for (int fd = 0; fd < 4; ++fd) {
                const bf16x8 bv = *(const bf16x8*)&Vs[(fd*16 + ln) * 64 + ((ks*32 + g*8) ^ rsw)];
                oacc[fd] = __builtin_amdgcn_mfma_f32_16x16x32_bf16(ap, bv, oacc[fd], 0, 0, 0);
            }
        }
        __syncthreads();
    }

    // ---- epilogue: bounce O through LDS (stride 68 floats), coalesced store ----
    float* Os = (float*)SH;   // 64*68*4 = 17408 B, overlays Qs/Ks/Vs (dead)
    float inv[4];
    #pragma unroll
    for (int r = 0; r < 4; ++r) inv[r] = 1.f / lrun[r];
    #pragma unroll
    for (int fd = 0; fd < 4; ++fd)
        #pragma unroll
        for (int r = 0; r < 4; ++r)
            Os[(fd*16 + ln) * 68 + w*16 + g*4 + r] = oacc[fd][r] * inv[r];
    __syncthreads();

    const int dh = tid >> 2, seg = tid & 3;
    #pragma unroll
    for (int t = 0; t < 4; ++t) {
        float4 v4;
        v4.x = Os[dh * 68 + seg*16 + t*4 + 0];
        v4.y = Os[dh * 68 + seg*16 + t*4 + 1];
        v4.z = Os[dh * 68 + seg*16 + t*4 + 2];
        v4.w = Os[dh * 68 + seg*16 + t*4 + 3];
        *(float4*)&out[((size_t)b * D_ + dh * H_ + h) * N_ + n0 + seg*16 + t*4] = v4;
    }
}

// ---------------------------------------------------------------------------
// InstanceNorm1d (affine=False) + ReLU, in place. One block per (b, channel).
// ---------------------------------------------------------------------------
__global__ __launch_bounds__(256) void inorm_relu(float* __restrict__ y)
{
    const int tid = threadIdx.x;
    float* row = y + (size_t)blockIdx.x * N_;
    float s = 0.f, s2 = 0.f;
    #pragma unroll
    for (int u = 0; u < 2; ++u) {
        const float4 v4 = *(const float4*)&row[u*1024 + tid*4];
        s  += v4.x + v4.y + v4.z + v4.w;
        s2 += v4.x*v4.x + v4.y*v4.y + v4.z*v4.z + v4.w*v4.w;
    }
    #pragma unroll
    for (int off = 1; off < 64; off <<= 1) {
        s  += __shfl_xor(s,  off);
        s2 += __shfl_xor(s2, off);
    }
    __shared__ float red[8];
    const int w = tid >> 6;
    if ((tid & 63) == 0) { red[w] = s; red[w + 4] = s2; }
    __syncthreads();
    s  = red[0] + red[1] + red[2] + red[3];
    s2 = red[4] + red[5] + red[6] + red[7];
    const float mean = s * (1.f / N_);
    const float var  = s2 * (1.f / N_) - mean * mean;
    const float inv  = rsqrtf(var + 1e-5f);
    #pragma unroll
    for (int u = 0; u < 2; ++u) {
        float4 v4 = *(float4*)&row[u*1024 + tid*4];
        v4.x = fmaxf((v4.x - mean) * inv, 0.f);
        v4.y = fmaxf((v4.y - mean) * inv, 0.f);
        v4.z = fmaxf((v4.z - mean) * inv, 0.f);
        v4.w = fmaxf((v4.w - mean) * inv, 0.f);
        *(float4*)&row[u*1024 + tid*4] = v4;
    }
}

// ---------------------------------------------------------------------------
extern "C" void kernel_launch(void* const* d_in, const int* in_sizes, int n_in,
                              void* d_out, int out_size, void* d_ws, size_t ws_size,
                              hipStream_t stream)
{
    const float* x    = (const float*)d_in[0];
    const float* srcp = (const float*)d_in[1];
    const float* mask = (const float*)d_in[2];
    const float* Wq = (const float*)d_in[3];
    const float* bq = (const float*)d_in[4];
    const float* Wk = (const float*)d_in[5];
    const float* bk = (const float*)d_in[6];
    const float* Wv = (const float*)d_in[7];
    const float* bv = (const float*)d_in[8];
    const float* Wm = (const float*)d_in[9];
    const float* bm = (const float*)d_in[10];
    const float* W1 = (const float*)d_in[11];
    const float* b1 = (const float*)d_in[12];
    const float* W2 = (const float*)d_in[13];
    const float* b2 = (const float*)d_in[14];
    float* out = (float*)d_out;

    // workspace layout (64 MiB):
    //   [ 0,16M): ab   fp32 [B,D,N]   attention output
    //   [16,32M): msg  fp32 [B,D,N]   merge output
    //   [32,40M): qt   bf16 [B,H,N,64]
    //   [40,48M): kt   bf16 [B,H,M,64]
    //   [48,56M): vbf  bf16 [B,D,M]
    //   [32,64M): y1   fp32 [B,2D,N]  (overlays qt/kt/vbf after attn+merge)
    char* wsb = (char*)d_ws;
    float* ab  = (float*)(wsb);
    float* msg = (float*)(wsb + (size_t)(16 << 20));
    unsigned short* qt_ = (unsigned short*)(wsb + (size_t)(32 << 20));
    unsigned short* kt_ = (unsigned short*)(wsb + (size_t)(40 << 20));
    unsigned short* vb_ = (unsigned short*)(wsb + (size_t)(48 << 20));
    float* y1  = (float*)(wsb + (size_t)(32 << 20));

    const dim3 blk(256);
    const dim3 g1(N_/64, D_/64, B_);

    pw_conv_qk<<<g1, blk, 0, stream>>>(Wq, bq, x,    qt_);
    pw_conv_qk<<<g1, blk, 0, stream>>>(Wk, bk, srcp, kt_);
    pw_conv_v <<<g1, blk, 0, stream>>>(Wv, bv, srcp, vb_);

    attn_mfma<<<dim3(N_/64, H_, B_), blk, 0, stream>>>(qt_, kt_, vb_, mask, ab);

    pw_conv<<<g1, blk, 0, stream>>>(Wm, bm, ab, ab, D_, D_, msg);

    pw_conv<<<dim3(N_/64, (2*D_)/64, B_), blk, 0, stream>>>(W1, b1, x, msg, D_, 2*D_, y1);

    inorm_relu<<<dim3(B_ * 2 * D_), blk, 0, stream>>>(y1);

    pw_conv<<<dim3(N_/64, D_/64, B_), blk, 0, stream>>>(W2, b2, y1, y1, 2*D_, 2*D_, out);
}

// Round 3
// 445.586 us; speedup vs baseline: 2.6961x; 1.6199x over previous
//
#include <hip/hip_runtime.h>
#include <hip/hip_bf16.h>
#include <math.h>

#define B_  8
#define D_  256
#define N_  2048
#define M_  2048
#define H_  4

typedef __attribute__((ext_vector_type(8))) short bf16x8;
typedef __attribute__((ext_vector_type(4))) float f32x4;

static __device__ __forceinline__ unsigned short f2bf(float f) {
    __hip_bfloat16 h = __float2bfloat16(f);
    return *reinterpret_cast<unsigned short*>(&h);
}
static __device__ __forceinline__ float bf2f_lo(unsigned int u) {
    return __uint_as_float((u & 0xffffu) << 16);
}
static __device__ __forceinline__ float bf2f_hi(unsigned int u) {
    return __uint_as_float(u & 0xffff0000u);
}

// global->LDS 16B async copy: per-lane GLOBAL src, wave-uniform LDS base (+lane*16 by HW)
#define GLOAD16(gsrc, ldsbase)                                                     \
    __builtin_amdgcn_global_load_lds(                                              \
        (const __attribute__((address_space(1))) unsigned int*)(gsrc),             \
        (__attribute__((address_space(3))) unsigned int*)(ldsbase), 16, 0, 0)

// ---------------------------------------------------------------------------
// Weight cast/permute kernel (one-time, ~656K elems).
//  wq_p/wk_p : rows permuted o' = h*64+dh  <- o = dh*4+h   (bf16)
//  wv        : natural                                      (bf16)
//  wm_p      : cols permuted c' = h*64+dh  <- c = dh*4+h    (bf16)
//  w1b, w2b  : natural                                      (bf16)
//  bq_p/bk_p : permuted biases                               (fp32)
// ---------------------------------------------------------------------------
__global__ __launch_bounds__(256) void cvt_w(
    const float* __restrict__ Wq, const float* __restrict__ Wk,
    const float* __restrict__ Wv, const float* __restrict__ Wm,
    const float* __restrict__ W1, const float* __restrict__ W2,
    const float* __restrict__ bq, const float* __restrict__ bk,
    unsigned short* __restrict__ wqp, unsigned short* __restrict__ wkp,
    unsigned short* __restrict__ wv,  unsigned short* __restrict__ wmp,
    unsigned short* __restrict__ w1b, unsigned short* __restrict__ w2b,
    float* __restrict__ bqp, float* __restrict__ bkp)
{
    const int idx = blockIdx.x * 256 + threadIdx.x;
    if (idx < 65536) {
        const int op = idx >> 8, k = idx & 255;
        const int h = op >> 6, dh = op & 63;
        wqp[idx] = f2bf(Wq[(dh*4 + h)*256 + k]);
    } else if (idx < 131072) {
        const int j = idx - 65536;
        const int op = j >> 8, k = j & 255;
        const int h = op >> 6, dh = op & 63;
        wkp[j] = f2bf(Wk[(dh*4 + h)*256 + k]);
    } else if (idx < 196608) {
        const int j = idx - 131072;
        wv[j] = f2bf(Wv[j]);
    } else if (idx < 262144) {
        const int j = idx - 196608;
        const int o = j >> 8, cp = j & 255;
        const int h = cp >> 6, dh = cp & 63;
        wmp[j] = f2bf(Wm[o*256 + dh*4 + h]);
    } else if (idx < 524288) {
        const int j = idx - 262144;
        w1b[j] = f2bf(W1[j]);
    } else if (idx < 655360) {
        const int j = idx - 524288;
        w2b[j] = f2bf(W2[j]);
    } else if (idx < 655616) {
        const int j = idx - 655360;
        const int h = j >> 6, dh = j & 63;
        bqp[j] = bq[dh*4 + h];
    } else {
        const int j = idx - 655616;
        const int h = j >> 6, dh = j & 63;
        bkp[j] = bk[dh*4 + h];
    }
}

// ---------------------------------------------------------------------------
// Transpose-convert x/source: fp32 [b,c,n] -> bf16 [b,n,c]. 64x64 tiles.
// grid (N/64, D/64, 2*B): z<8 -> x->xbf, else source->srcbf
// ---------------------------------------------------------------------------
__global__ __launch_bounds__(256) void cvt_t(
    const float* __restrict__ x, const float* __restrict__ src,
    unsigned short* __restrict__ xbf, unsigned short* __restrict__ sbf)
{
    __shared__ float T[64][65];
    const int z = blockIdx.z;
    const int b = z & 7;
    const float* in = (z < 8) ? x : src;
    unsigned short* out = (z < 8) ? xbf : sbf;
    const int c0 = blockIdx.y * 64, n0 = blockIdx.x * 64;
    const int tid = threadIdx.x;
    #pragma unroll
    for (int u = 0; u < 16; ++u) {
        const int idx = u * 256 + tid;
        const int nn = idx & 63, cc = idx >> 6;
        T[cc][nn] = in[((size_t)(b*256 + c0 + cc))*2048 + n0 + nn];
    }
    __syncthreads();
    #pragma unroll
    for (int u = 0; u < 16; ++u) {
        const int idx = u * 256 + tid;
        const int c = idx & 63, nn = idx >> 6;
        out[((size_t)(b*2048 + n0 + nn))*256 + c0 + c] = f2bf(T[c][nn]);
    }
}

// ---------------------------------------------------------------------------
// MFMA pointwise conv: out[b,n,o-tile] = W[o][k] . in[b,n,k] + bias
// Tile 128o x 128n, BK=64, 4 waves (2x2), per-wave 64x64 (4x4 frags 16x16x32).
// Double-buffered LDS, global_load_lds(16B) staging with rule-#21 swizzle:
// linear LDS dest + inverse-XOR'd global source + XOR'd ds_read.
// Virtual concat along channels via (inA, inB, splitC).
// EPI: 0 = bf16 [b,h,n,dh] (q/k, permuted weights)
//      1 = bf16 [b,o,m] channel-major (v)
//      2 = bf16 [b,n,Cout] position-major (msg / y1)
//      4 = fp32 [b,o,n] channel-major (final output)
// ---------------------------------------------------------------------------
template<int CIN, int EPI>
__global__ __launch_bounds__(256, 2) void conv_mfma(
    const unsigned short* __restrict__ Wb, const float* __restrict__ bias,
    const unsigned short* __restrict__ inA, const unsigned short* __restrict__ inB,
    int splitC, void* __restrict__ outp)
{
    __shared__ __align__(16) unsigned short SH[32768];   // 64 KB: 2 x (As 16K + Bs 16K)
    const int b  = blockIdx.z;
    const int o0 = blockIdx.y * 128;
    const int n0 = blockIdx.x * 128;
    const int tid = threadIdx.x;
    const int w = tid >> 6, l = tid & 63;
    const int wr = w >> 1, wc = w & 1;
    const int g_ = l >> 4, ln = l & 15;

    f32x4 acc[4][4];
    #pragma unroll
    for (int mi = 0; mi < 4; ++mi)
        #pragma unroll
        for (int nj = 0; nj < 4; ++nj) acc[mi][nj] = (f32x4){0.f, 0.f, 0.f, 0.f};

    auto STAGE = [&](int t, int c) {
        const int k0 = t * 64;
        unsigned short* As = SH + c * 16384;
        unsigned short* Bs = As + 8192;
        #pragma unroll
        for (int u = 0; u < 4; ++u) {
            const int chunk = (w*4 + u)*64 + l;
            const int row = chunk >> 3;
            const int cs = (chunk & 7) ^ (row & 7);
            const unsigned short* gp = Wb + (size_t)(o0 + row)*CIN + k0 + cs*8;
            GLOAD16(gp, As + (w*4 + u)*512);
        }
        const unsigned short* src; int sC, kk;
        if (k0 < splitC) { src = inA; sC = splitC; kk = k0; }
        else             { src = inB; sC = CIN - splitC; kk = k0 - splitC; }
        #pragma unroll
        for (int u = 0; u < 4; ++u) {
            const int chunk = (w*4 + u)*64 + l;
            const int row = chunk >> 3;
            const int cs = (chunk & 7) ^ (row & 7);
            const unsigned short* gp = src + ((size_t)b*N_ + n0 + row)*sC + kk + cs*8;
            GLOAD16(gp, Bs + (w*4 + u)*512);
        }
    };

    auto COMPUTE = [&](int c) {
        const unsigned short* As = SH + c * 16384;
        const unsigned short* Bs = As + 8192;
        #pragma unroll
        for (int ks = 0; ks < 2; ++ks) {
            bf16x8 af[4], bfr[4];
            #pragma unroll
            for (int mi = 0; mi < 4; ++mi) {
                const int row = wr*64 + mi*16 + ln;
                af[mi] = *(const bf16x8*)&As[row*64 + (((ks*4 + g_) ^ (row & 7)) << 3)];
            }
            #pragma unroll
            for (int nj = 0; nj < 4; ++nj) {
                const int row = wc*64 + nj*16 + ln;
                bfr[nj] = *(const bf16x8*)&Bs[row*64 + (((ks*4 + g_) ^ (row & 7)) << 3)];
            }
            #pragma unroll
            for (int mi = 0; mi < 4; ++mi)
                #pragma unroll
                for (int nj = 0; nj < 4; ++nj)
                    acc[mi][nj] = __builtin_amdgcn_mfma_f32_16x16x32_bf16(af[mi], bfr[nj], acc[mi][nj], 0, 0, 0);
        }
    };

    const int nt = CIN / 64;
    STAGE(0, 0);
    __syncthreads();
    int cur = 0;
    for (int t = 0; t < nt; ++t) {
        if (t + 1 < nt) STAGE(t + 1, cur ^ 1);
        COMPUTE(cur);
        __syncthreads();
        cur ^= 1;
    }

    // ---------------- epilogues (acc frag: o = wr*64+mi*16+g_*4+r, n = wc*64+nj*16+ln)
    if constexpr (EPI == 0 || EPI == 2) {
        unsigned short* Os = SH;   // [128 n][128 o] bf16, 16B-chunk XOR swizzle
        #pragma unroll
        for (int mi = 0; mi < 4; ++mi) {
            const int ob = wr*64 + mi*16 + g_*4;
            const float4 bv = *(const float4*)&bias[o0 + ob];
            #pragma unroll
            for (int nj = 0; nj < 4; ++nj) {
                const int nl = wc*64 + nj*16 + ln;
                ushort4 us;
                us.x = f2bf(acc[mi][nj][0] + bv.x);
                us.y = f2bf(acc[mi][nj][1] + bv.y);
                us.z = f2bf(acc[mi][nj][2] + bv.z);
                us.w = f2bf(acc[mi][nj][3] + bv.w);
                *(ushort4*)&Os[nl*128 + (((ob >> 3) ^ (nl & 7)) << 3) + (ob & 4)] = us;
            }
        }
        __syncthreads();
        if constexpr (EPI == 0) {
            unsigned short* outT = (unsigned short*)outp;   // [b,h,n,64]
            #pragma unroll
            for (int u = 0; u < 8; ++u) {
                const int idx = u*256 + tid;
                const int oc = idx & 15, n = idx >> 4;
                const uint4 v = *(const uint4*)&Os[n*128 + ((oc ^ (n & 7)) << 3)];
                const int og = o0 + oc*8;
                *(uint4*)&outT[(((size_t)b*H_ + (og >> 6))*N_ + n0 + n)*64 + (og & 63)] = v;
            }
        } else {
            unsigned short* outS = (unsigned short*)outp;   // [b,n,Cout]
            const int ostride = gridDim.y * 128;
            #pragma unroll
            for (int u = 0; u < 8; ++u) {
                const int idx = u*256 + tid;
                const int oc = idx & 15, n = idx >> 4;
                const uint4 v = *(const uint4*)&Os[n*128 + ((oc ^ (n & 7)) << 3)];
                *(uint4*)&outS[((size_t)b*N_ + n0 + n)*ostride + o0 + oc*8] = v;
            }
        }
    } else if constexpr (EPI == 1) {
        unsigned short* Os = SH;   // [128 o][136 m] bf16, padded
        #pragma unroll
        for (int mi = 0; mi < 4; ++mi) {
            const int ob = wr*64 + mi*16 + g_*4;
            const float4 bv = *(const float4*)&bias[o0 + ob];
            const float bb[4] = {bv.x, bv.y, bv.z, bv.w};
            #pragma unroll
            for (int nj = 0; nj < 4; ++nj) {
                const int nl = wc*64 + nj*16 + ln;
                #pragma unroll
                for (int r = 0; r < 4; ++r)
                    Os[(ob + r)*136 + nl] = f2bf(acc[mi][nj][r] + bb[r]);
            }
        }
        __syncthreads();
        unsigned short* outV = (unsigned short*)outp;   // [b,o,m]
        #pragma unroll
        for (int u = 0; u < 8; ++u) {
            const int idx = u*256 + tid;
            const int mc = idx & 15, o = idx >> 4;
            const uint4 v = *(const uint4*)&Os[o*136 + mc*8];
            *(uint4*)&outV[((size_t)b*D_ + o0 + o)*(size_t)M_ + n0 + mc*8] = v;
        }
    } else {   // EPI == 4: fp32 [b,o,n]
        float* Of = (float*)SH;   // [128 o][128 n] fp32, 16B-chunk XOR swizzle
        #pragma unroll
        for (int mi = 0; mi < 4; ++mi) {
            const int ob = wr*64 + mi*16 + g_*4;
            const float4 bv = *(const float4*)&bias[o0 + ob];
            const float bb[4] = {bv.x, bv.y, bv.z, bv.w};
            #pragma unroll
            for (int nj = 0; nj < 4; ++nj) {
                const int nl = wc*64 + nj*16 + ln;
                #pragma unroll
                for (int r = 0; r < 4; ++r) {
                    const int o_ = ob + r;
                    Of[o_*128 + ((((nl >> 2) ^ (o_ & 7)) << 2)) + (nl & 3)] = acc[mi][nj][r] + bb[r];
                }
            }
        }
        __syncthreads();
        float* outF = (float*)outp;
        #pragma unroll
        for (int u = 0; u < 16; ++u) {
            const int idx = u*256 + tid;
            const int nc = idx & 31, o = idx >> 5;
            const float4 v = *(const float4*)&Of[o*128 + ((nc ^ (o & 7)) << 2)];
            *(float4*)&outF[((size_t)b*D_ + o0 + o)*(size_t)N_ + n0 + nc*4] = v;
        }
    }
}

// ---------------------------------------------------------------------------
// MFMA flash attention (unchanged core from round 2; new bf16 [b,n,h*64+dh] out)
// ---------------------------------------------------------------------------
__global__ __launch_bounds__(256) void attn_mfma(
    const unsigned short* __restrict__ qt, const unsigned short* __restrict__ kt,
    const unsigned short* __restrict__ vbf, const float* __restrict__ mask,
    unsigned short* __restrict__ ab)
{
    __shared__ __align__(16) unsigned short SH[4 * 64 * 64];   // Qs|Ks|Vs|Ps, 32 KB
    unsigned short* Qs = SH;
    unsigned short* Ks = SH + 4096;
    unsigned short* Vs = SH + 8192;
    unsigned short* Ps = SH + 12288;

    const int b = blockIdx.z, h = blockIdx.y, n0 = blockIdx.x * 64;
    const int tid = threadIdx.x;
    const int w = tid >> 6, lane = tid & 63;
    const int ln = lane & 15, g = lane >> 4;
    const int rsw = (ln & 7) << 3;

    #pragma unroll
    for (int u = 0; u < 4; ++u) {
        const int idx = u * 256 + tid;
        const int ch = idx & 15, n = idx >> 4;
        const ushort4 v = *(const ushort4*)&qt[(((size_t)b * H_ + h) * N_ + n0 + n) * 64 + ch*4];
        *(ushort4*)&Qs[n * 64 + ((ch*4) ^ ((n & 7) << 3))] = v;
    }

    f32x4 oacc[4];
    #pragma unroll
    for (int f = 0; f < 4; ++f) oacc[f] = (f32x4){0.f, 0.f, 0.f, 0.f};
    float mrun[4] = {-INFINITY, -INFINITY, -INFINITY, -INFINITY};
    float lrun[4] = {0.f, 0.f, 0.f, 0.f};

    __syncthreads();

    bf16x8 a_q[2];
    #pragma unroll
    for (int ks = 0; ks < 2; ++ks)
        a_q[ks] = *(const bf16x8*)&Qs[(w*16 + ln) * 64 + ((ks*32 + g*8) ^ rsw)];

    for (int m0 = 0; m0 < M_; m0 += 64) {
        #pragma unroll
        for (int u = 0; u < 4; ++u) {
            const int idx = u * 256 + tid;
            const int ch = idx & 15, r = idx >> 4;
            const ushort4 kv = *(const ushort4*)&kt[(((size_t)b * H_ + h) * M_ + m0 + r) * 64 + ch*4];
            *(ushort4*)&Ks[r * 64 + ((ch*4) ^ ((r & 7) << 3))] = kv;
            const ushort4 vv = *(const ushort4*)&vbf[((size_t)b * D_ + r * H_ + h) * M_ + m0 + ch*4];
            *(ushort4*)&Vs[r * 64 + ((ch*4) ^ ((r & 7) << 3))] = vv;
        }
        __syncthreads();

        float mk[4][4];
        #pragma unroll
        for (int r = 0; r < 4; ++r)
            #pragma unroll
            for (int f = 0; f < 4; ++f)
                mk[r][f] = mask[((size_t)b * N_ + n0 + w*16 + g*4 + r) * (size_t)M_ + m0 + f*16 + ln];

        f32x4 sacc[4];
        #pragma unroll
        for (int f = 0; f < 4; ++f) sacc[f] = (f32x4){0.f, 0.f, 0.f, 0.f};
        #pragma unroll
        for (int ks = 0; ks < 2; ++ks)
            #pragma unroll
            for (int f = 0; f < 4; ++f) {
                const bf16x8 bk = *(const bf16x8*)&Ks[(f*16 + ln) * 64 + ((ks*32 + g*8) ^ rsw)];
                sacc[f] = __builtin_amdgcn_mfma_f32_16x16x32_bf16(a_q[ks], bk, sacc[f], 0, 0, 0);
            }

        #pragma unroll
        for (int r = 0; r < 4; ++r) {
            float s0 = sacc[0][r] * 0.125f * mk[r][0];
            float s1 = sacc[1][r] * 0.125f * mk[r][1];
            float s2 = sacc[2][r] * 0.125f * mk[r][2];
            float s3 = sacc[3][r] * 0.125f * mk[r][3];
            float tmax = fmaxf(fmaxf(s0, s1), fmaxf(s2, s3));
            tmax = fmaxf(tmax, __shfl_xor(tmax, 1, 16));
            tmax = fmaxf(tmax, __shfl_xor(tmax, 2, 16));
            tmax = fmaxf(tmax, __shfl_xor(tmax, 4, 16));
            tmax = fmaxf(tmax, __shfl_xor(tmax, 8, 16));
            const float nm = fmaxf(mrun[r], tmax);
            const float corr = __expf(mrun[r] - nm);
            const float p0 = __expf(s0 - nm);
            const float p1 = __expf(s1 - nm);
            const float p2 = __expf(s2 - nm);
            const float p3 = __expf(s3 - nm);
            float ps = p0 + p1 + p2 + p3;
            ps += __shfl_xor(ps, 1, 16);
            ps += __shfl_xor(ps, 2, 16);
            ps += __shfl_xor(ps, 4, 16);
            ps += __shfl_xor(ps, 8, 16);
            lrun[r] = lrun[r] * corr + ps;
            mrun[r] = nm;
            #pragma unroll
            for (int f = 0; f < 4; ++f) oacc[f][r] *= corr;
            const int row = w*16 + g*4 + r;
            const int rs2 = (row & 7) << 3;
            Ps[row * 64 + ((0*16 + ln) ^ rs2)] = f2bf(p0);
            Ps[row * 64 + ((1*16 + ln) ^ rs2)] = f2bf(p1);
            Ps[row * 64 + ((2*16 + ln) ^ rs2)] = f2bf(p2);
            Ps[row * 64 + ((3*16 + ln) ^ rs2)] = f2bf(p3);
        }
        __syncthreads();

        #pragma unroll
        for (int ks = 0; ks < 2; ++ks) {
            const bf16x8 ap = *(const bf16x8*)&Ps[(w*16 + ln) * 64 + ((ks*32 + g*8) ^ rsw)];
            #pragma unroll
            for (int fd = 0; fd < 4; ++fd) {
                const bf16x8 bv = *(const bf16x8*)&Vs[(fd*16 + ln) * 64 + ((ks*32 + g*8) ^ rsw)];
                oacc[fd] = __builtin_amdgcn_mfma_f32_16x16x32_bf16(ap, bv, oacc[fd], 0, 0, 0);
            }
        }
        __syncthreads();
    }

    // epilogue: O -> bf16 ab[b, n, h*64+dh] via swizzled LDS bounce (8 KB, Qs region)
    unsigned short* Os = SH;
    float inv[4];
    #pragma unroll
    for (int r = 0; r < 4; ++r) inv[r] = 1.f / lrun[r];
    #pragma unroll
    for (int fd = 0; fd < 4; ++fd) {
        const int dh = fd*16 + ln;
        const int cd = dh >> 3;
        #pragma unroll
        for (int r = 0; r < 4; ++r) {
            const int n = w*16 + g*4 + r;
            Os[n*64 + ((cd ^ (n & 7)) << 3) + (dh & 7)] = f2bf(oacc[fd][r] * inv[r]);
        }
    }
    __syncthreads();
    #pragma unroll
    for (int u = 0; u < 2; ++u) {
        const int idx = u*256 + tid;
        const int ch = idx & 7, n = idx >> 3;
        const uint4 v = *(const uint4*)&Os[n*64 + ((ch ^ (n & 7)) << 3)];
        *(uint4*)&ab[((size_t)b*N_ + n0 + n)*256 + h*64 + ch*8] = v;
    }
}

// ---------------------------------------------------------------------------
// InstanceNorm over n per (b,c): stats pass (block partials + atomics), then apply.
// y1: bf16 [b,n,512]; st: fp32 [b][512][2] (pre-zeroed); yo: bf16 [b,n,512]
// ---------------------------------------------------------------------------
__global__ __launch_bounds__(256) void in_stats(
    const unsigned short* __restrict__ y1, float* __restrict__ st)
{
    const int b = blockIdx.y, nch = blockIdx.x, tid = threadIdx.x;
    const int c = tid * 2;
    float sa = 0.f, sa2 = 0.f, sb = 0.f, sb2 = 0.f;
    for (int r = 0; r < 128; ++r) {
        const int n = nch*128 + r;
        const unsigned int u = *(const unsigned int*)&y1[((size_t)b*N_ + n)*512 + c];
        const float a = bf2f_lo(u), bb = bf2f_hi(u);
        sa += a; sa2 += a*a; sb += bb; sb2 += bb*bb;
    }
    atomicAdd(&st[(b*512 + c)*2 + 0], sa);
    atomicAdd(&st[(b*512 + c)*2 + 1], sa2);
    atomicAdd(&st[(b*512 + c + 1)*2 + 0], sb);
    atomicAdd(&st[(b*512 + c + 1)*2 + 1], sb2);
}

__global__ __launch_bounds__(256) void in_apply(
    const unsigned short* __restrict__ y1, const float* __restrict__ st,
    unsigned short* __restrict__ yo)
{
    const int b = blockIdx.y, nch = blockIdx.x, tid = threadIdx.x;
    const int c = tid * 2;
    const float mua = st[(b*512 + c)*2 + 0] * (1.f/2048.f);
    const float vara = st[(b*512 + c)*2 + 1] * (1.f/2048.f) - mua*mua;
    const float inva = rsqrtf(vara + 1e-5f);
    const float mub = st[(b*512 + c + 1)*2 + 0] * (1.f/2048.f);
    const float varb = st[(b*512 + c + 1)*2 + 1] * (1.f/2048.f) - mub*mub;
    const float invb = rsqrtf(varb + 1e-5f);
    for (int r = 0; r < 128; ++r) {
        const int n = nch*128 + r;
        const size_t off = ((size_t)b*N_ + n)*512 + c;
        const unsigned int u = *(const unsigned int*)&y1[off];
        const float na = fmaxf((bf2f_lo(u) - mua) * inva, 0.f);
        const float nb = fmaxf((bf2f_hi(u) - mub) * invb, 0.f);
        const unsigned int pv = (unsigned int)f2bf(na) | ((unsigned int)f2bf(nb) << 16);
        *(unsigned int*)&yo[off] = pv;
    }
}

// ---------------------------------------------------------------------------
extern "C" void kernel_launch(void* const* d_in, const int* in_sizes, int n_in,
                              void* d_out, int out_size, void* d_ws, size_t ws_size,
                              hipStream_t stream)
{
    const float* x    = (const float*)d_in[0];
    const float* srcp = (const float*)d_in[1];
    const float* mask = (const float*)d_in[2];
    const float* Wq = (const float*)d_in[3];
    const float* bq = (const float*)d_in[4];
    const float* Wk = (const float*)d_in[5];
    const float* bk = (const float*)d_in[6];
    const float* Wv = (const float*)d_in[7];
    const float* bv = (const float*)d_in[8];
    const float* Wm = (const float*)d_in[9];
    const float* bm = (const float*)d_in[10];
    const float* W1 = (const float*)d_in[11];
    const float* b1 = (const float*)d_in[12];
    const float* W2 = (const float*)d_in[13];
    const float* b2 = (const float*)d_in[14];
    float* out = (float*)d_out;

    // workspace (~57.3 MiB):
    char* wsb = (char*)d_ws;
    const size_t MB = 1 << 20;
    unsigned short* xbf   = (unsigned short*)(wsb + 0*MB);    // [b,n,256] bf16
    unsigned short* srcbf = (unsigned short*)(wsb + 8*MB);    // [b,m,256] bf16
    unsigned short* ab    = (unsigned short*)(wsb + 8*MB);    // reuses srcbf after qkv convs
    unsigned short* qt_   = (unsigned short*)(wsb + 16*MB);   // [b,h,n,64]
    unsigned short* msg   = (unsigned short*)(wsb + 16*MB);   // reuses qt after attn
    unsigned short* kt_   = (unsigned short*)(wsb + 24*MB);   // [b,h,m,64]
    unsigned short* y1    = (unsigned short*)(wsb + 24*MB);   // [b,n,512] (over kt+vbf, after attn)
    unsigned short* vb_   = (unsigned short*)(wsb + 32*MB);   // [b,d,m]
    unsigned short* ybf   = (unsigned short*)(wsb + 40*MB);   // [b,n,512]
    char* wbase = wsb + 56*MB;
    unsigned short* wqp = (unsigned short*)(wbase + 0);
    unsigned short* wkp = (unsigned short*)(wbase + 128*1024);
    unsigned short* wv  = (unsigned short*)(wbase + 256*1024);
    unsigned short* wmp = (unsigned short*)(wbase + 384*1024);
    unsigned short* w1b = (unsigned short*)(wbase + 512*1024);
    unsigned short* w2b = (unsigned short*)(wbase + 1024*1024);
    float* bqp   = (float*)(wbase + 1280*1024);
    float* bkp   = (float*)(wbase + 1281*1024);
    float* stats = (float*)(wbase + 1282*1024);               // [8][512][2] fp32

    const dim3 blk(256);

    cvt_w<<<dim3(2562), blk, 0, stream>>>(Wq, Wk, Wv, Wm, W1, W2, bq, bk,
                                          wqp, wkp, wv, wmp, w1b, w2b, bqp, bkp);
    cvt_t<<<dim3(32, 4, 16), blk, 0, stream>>>(x, srcp, xbf, srcbf);
    hipMemsetAsync(stats, 0, 8*512*2*sizeof(float), stream);

    conv_mfma<256, 0><<<dim3(16, 2, 8), blk, 0, stream>>>(wqp, bqp, xbf,   xbf, 256, qt_);
    conv_mfma<256, 0><<<dim3(16, 2, 8), blk, 0, stream>>>(wkp, bkp, srcbf, srcbf, 256, kt_);
    conv_mfma<256, 1><<<dim3(16, 2, 8), blk, 0, stream>>>(wv,  bv,  srcbf, srcbf, 256, vb_);

    attn_mfma<<<dim3(32, 4, 8), blk, 0, stream>>>(qt_, kt_, vb_, mask, ab);

    conv_mfma<256, 2><<<dim3(16, 2, 8), blk, 0, stream>>>(wmp, bm, ab, ab, 256, msg);
    conv_mfma<512, 2><<<dim3(16, 4, 8), blk, 0, stream>>>(w1b, b1, xbf, msg, 256, y1);

    in_stats<<<dim3(16, 8), blk, 0, stream>>>(y1, stats);
    in_apply<<<dim3(16, 8), blk, 0, stream>>>(y1, stats, ybf);

    conv_mfma<512, 4><<<dim3(16, 2, 8), blk, 0, stream>>>(w2b, b2, ybf, ybf, 512, out);
}